// Round 1
// baseline (437.081 us; speedup 1.0000x reference)
//
#include <hip/hip_runtime.h>
#include <hip/hip_bf16.h>
#include <math.h>

#define H 1024
#define V 50257
#define S 2048

// d_out layout (floats): [0, V) log_probs | [V, V+H) h_new | [V+H, V+H+S) attn
#define OUT_LP   0
#define OUT_H    50257
#define OUT_ATTN 51281

// workspace layout (floats)
#define WS_ALOG 0        // 2048 attention logits
#define WS_CTX  2048     // 1024 context accumulator (zeroed by K2a)
#define WS_COMB 3072     // 1024 combined vector
#define WS_PMAX 4096     // 1571 per-block max
#define WS_PSUM 5696     // 1571 per-block sumexp
#define WS_MS   7296     // 2: global max, log(sum)

#define K4_NB 1571       // ceil(50257 / 32)

// ---------------- K1: embedding + relu + GRU cell -> h_new ----------------
__global__ void gru_kernel(const int* __restrict__ ids,
                           const float* __restrict__ hidden,
                           const float* __restrict__ emb,
                           const float* __restrict__ W_ih,
                           const float* __restrict__ W_hh,
                           const float* __restrict__ b_ih,
                           const float* __restrict__ b_hh,
                           float* __restrict__ hnew_out) {
    __shared__ float x_lds[H];
    __shared__ float h_lds[H];
    const int tid = threadIdx.x;
    const int row = ids[0];
    const float* erow = emb + (size_t)row * H;
    for (int i = tid; i < H; i += 256) {
        x_lds[i] = fmaxf(erow[i], 0.0f);
        h_lds[i] = hidden[i];
    }
    __syncthreads();

    const int lane = tid & 63;
    const int w    = tid >> 6;
    const int j    = blockIdx.x * 4 + w;   // grid = 256 blocks -> j in [0,1024)

    const float4* x4  = (const float4*)x_lds;
    const float4* h4  = (const float4*)h_lds;
    const float4* Wi4 = (const float4*)W_ih;
    const float4* Wh4 = (const float4*)W_hh;

    float air = 0.f, aiz = 0.f, ain = 0.f, ahr = 0.f, ahz = 0.f, ahn = 0.f;
#pragma unroll
    for (int i = 0; i < 4; ++i) {
        const int idx = i * 64 + lane;
        const float4 xv = x4[idx];
        const float4 hv = h4[idx];
        float4 a = Wi4[(size_t)j * 256 + idx];
        air += a.x * xv.x + a.y * xv.y + a.z * xv.z + a.w * xv.w;
        float4 b = Wi4[(size_t)(H + j) * 256 + idx];
        aiz += b.x * xv.x + b.y * xv.y + b.z * xv.z + b.w * xv.w;
        float4 c = Wi4[(size_t)(2 * H + j) * 256 + idx];
        ain += c.x * xv.x + c.y * xv.y + c.z * xv.z + c.w * xv.w;
        float4 d = Wh4[(size_t)j * 256 + idx];
        ahr += d.x * hv.x + d.y * hv.y + d.z * hv.z + d.w * hv.w;
        float4 e = Wh4[(size_t)(H + j) * 256 + idx];
        ahz += e.x * hv.x + e.y * hv.y + e.z * hv.z + e.w * hv.w;
        float4 f = Wh4[(size_t)(2 * H + j) * 256 + idx];
        ahn += f.x * hv.x + f.y * hv.y + f.z * hv.z + f.w * hv.w;
    }
#pragma unroll
    for (int off = 32; off > 0; off >>= 1) {
        air += __shfl_down(air, off);
        aiz += __shfl_down(aiz, off);
        ain += __shfl_down(ain, off);
        ahr += __shfl_down(ahr, off);
        ahz += __shfl_down(ahz, off);
        ahn += __shfl_down(ahn, off);
    }
    if (lane == 0) {
        const float gir = air + b_ih[j];
        const float giz = aiz + b_ih[H + j];
        const float gin = ain + b_ih[2 * H + j];
        const float ghr = ahr + b_hh[j];
        const float ghz = ahz + b_hh[H + j];
        const float ghn = ahn + b_hh[2 * H + j];
        const float r = 1.0f / (1.0f + expf(-(gir + ghr)));
        const float z = 1.0f / (1.0f + expf(-(giz + ghz)));
        const float n = tanhf(gin + r * ghn);
        hnew_out[j] = (1.0f - z) * n + z * h_lds[j];
    }
}

// ---------------- K2a: attention logits + zero ctx ----------------
__global__ void attnlogits_kernel(const float* __restrict__ enc,
                                  const float* __restrict__ hnew,
                                  float* __restrict__ alog,
                                  float* __restrict__ ctx) {
    __shared__ float h_lds[H];
    const int tid = threadIdx.x;
    for (int i = tid; i < H; i += 256) h_lds[i] = hnew[i];
    if (blockIdx.x == 0) {
        for (int i = tid; i < H; i += 256) ctx[i] = 0.0f;
    }
    __syncthreads();

    const int lane = tid & 63;
    const int w    = tid >> 6;
    const int s    = blockIdx.x * 4 + w;   // grid = 512 blocks -> s in [0,2048)

    const float4* h4 = (const float4*)h_lds;
    const float4* e4 = (const float4*)(enc + (size_t)s * H);
    float acc = 0.f;
#pragma unroll
    for (int i = 0; i < 4; ++i) {
        const int idx = i * 64 + lane;
        const float4 ev = e4[idx];
        const float4 hv = h4[idx];
        acc += ev.x * hv.x + ev.y * hv.y + ev.z * hv.z + ev.w * hv.w;
    }
#pragma unroll
    for (int off = 32; off > 0; off >>= 1) acc += __shfl_down(acc, off);
    if (lane == 0) alog[s] = acc;
}

// ---------------- K2c: softmax + ctx accumulation + attn output ----------------
__global__ void attn_ctx_kernel(const float* __restrict__ enc,
                                const float* __restrict__ alog,
                                float* __restrict__ ctx,
                                float* __restrict__ out_attn) {
    __shared__ float l_lds[S];
    __shared__ float red[256];
    const int tid = threadIdx.x;
    for (int i = tid; i < S; i += 256) l_lds[i] = alog[i];
    __syncthreads();

    // block-redundant max over 2048
    float m = -INFINITY;
    for (int i = tid; i < S; i += 256) m = fmaxf(m, l_lds[i]);
    red[tid] = m;
    __syncthreads();
    for (int s = 128; s > 0; s >>= 1) {
        if (tid < s) red[tid] = fmaxf(red[tid], red[tid + s]);
        __syncthreads();
    }
    m = red[0];
    __syncthreads();

    float ssum = 0.f;
    for (int i = tid; i < S; i += 256) ssum += expf(l_lds[i] - m);
    red[tid] = ssum;
    __syncthreads();
    for (int s = 128; s > 0; s >>= 1) {
        if (tid < s) red[tid] += red[tid + s];
        __syncthreads();
    }
    const float inv = 1.0f / red[0];

    // each block accumulates 32 rows into a per-thread float4 partial
    const int s0 = blockIdx.x * 32;   // grid = 64 blocks
    float4 cacc = make_float4(0.f, 0.f, 0.f, 0.f);
    const float4* e4 = (const float4*)enc;
    for (int r = 0; r < 32; ++r) {
        const int srow = s0 + r;
        const float wgt = expf(l_lds[srow] - m) * inv;
        const float4 ev = e4[(size_t)srow * 256 + tid];
        cacc.x += wgt * ev.x;
        cacc.y += wgt * ev.y;
        cacc.z += wgt * ev.z;
        cacc.w += wgt * ev.w;
    }
    atomicAdd(&ctx[tid * 4 + 0], cacc.x);
    atomicAdd(&ctx[tid * 4 + 1], cacc.y);
    atomicAdd(&ctx[tid * 4 + 2], cacc.z);
    atomicAdd(&ctx[tid * 4 + 3], cacc.w);

    if (tid < 32) {
        const int srow = s0 + tid;
        out_attn[srow] = expf(l_lds[srow] - m) * inv;
    }
}

// ---------------- K3: comb = tanh(W_comb @ [ctx; h_new] + b_comb) ----------------
__global__ void comb_kernel(const float* __restrict__ W_comb,
                            const float* __restrict__ b_comb,
                            const float* __restrict__ ctx,
                            const float* __restrict__ hnew,
                            float* __restrict__ comb) {
    __shared__ float cat_lds[2 * H];
    const int tid = threadIdx.x;
    for (int i = tid; i < H; i += 256) {
        cat_lds[i]     = ctx[i];
        cat_lds[H + i] = hnew[i];
    }
    __syncthreads();

    const int lane = tid & 63;
    const int w    = tid >> 6;
    const int j    = blockIdx.x * 4 + w;   // grid = 256 blocks

    const float4* c4 = (const float4*)cat_lds;
    const float4* W4 = (const float4*)(W_comb + (size_t)j * 2 * H);
    float acc = 0.f;
#pragma unroll
    for (int i = 0; i < 8; ++i) {
        const int idx = i * 64 + lane;
        const float4 wv = W4[idx];
        const float4 cv = c4[idx];
        acc += wv.x * cv.x + wv.y * cv.y + wv.z * cv.z + wv.w * cv.w;
    }
#pragma unroll
    for (int off = 32; off > 0; off >>= 1) acc += __shfl_down(acc, off);
    if (lane == 0) comb[j] = tanhf(acc + b_comb[j]);
}

// ---------------- K4a: logits = W_out @ comb + b_out, per-block (max,sumexp) ----------------
__global__ void outproj_kernel(const float* __restrict__ Wout,
                               const float* __restrict__ bout,
                               const float* __restrict__ comb,
                               float* __restrict__ logits_out,
                               float* __restrict__ pmax,
                               float* __restrict__ psum) {
    __shared__ float c_lds[H];
    __shared__ float l_blk[32];
    const int tid = threadIdx.x;
    for (int i = tid; i < H; i += 256) c_lds[i] = comb[i];
    __syncthreads();

    const int lane = tid & 63;
    const int w    = tid >> 6;
    const float4* c4 = (const float4*)c_lds;
    const int rbase = (blockIdx.x * 4 + w) * 8;   // 8 rows per wave, 32 per block

    for (int r = 0; r < 8; ++r) {
        const int row = rbase + r;
        float acc = 0.f;
        if (row < V) {
            const float4* W4 = (const float4*)(Wout + (size_t)row * H);
#pragma unroll
            for (int i = 0; i < 4; ++i) {
                const int idx = i * 64 + lane;
                const float4 wv = W4[idx];
                const float4 cv = c4[idx];
                acc += wv.x * cv.x + wv.y * cv.y + wv.z * cv.z + wv.w * cv.w;
            }
        }
#pragma unroll
        for (int off = 32; off > 0; off >>= 1) acc += __shfl_down(acc, off);
        if (lane == 0) {
            float l = -INFINITY;
            if (row < V) {
                l = acc + bout[row];
                logits_out[row] = l;
            }
            l_blk[w * 8 + r] = l;
        }
    }
    __syncthreads();
    if (tid == 0) {
        float m = -INFINITY;
#pragma unroll
        for (int i = 0; i < 32; ++i) m = fmaxf(m, l_blk[i]);
        float ssum = 0.f;
#pragma unroll
        for (int i = 0; i < 32; ++i) ssum += expf(l_blk[i] - m);
        pmax[blockIdx.x] = m;
        psum[blockIdx.x] = ssum;
    }
}

// ---------------- K4b: merge per-block (max,sumexp) pairs ----------------
__global__ void lse_merge_kernel(const float* __restrict__ pmax,
                                 const float* __restrict__ psum,
                                 float* __restrict__ ms) {
    __shared__ float red[256];
    const int tid = threadIdx.x;
    float m = -INFINITY;
    for (int i = tid; i < K4_NB; i += 256) m = fmaxf(m, pmax[i]);
    red[tid] = m;
    __syncthreads();
    for (int s = 128; s > 0; s >>= 1) {
        if (tid < s) red[tid] = fmaxf(red[tid], red[tid + s]);
        __syncthreads();
    }
    m = red[0];
    __syncthreads();
    float ssum = 0.f;
    for (int i = tid; i < K4_NB; i += 256) ssum += psum[i] * expf(pmax[i] - m);
    red[tid] = ssum;
    __syncthreads();
    for (int s = 128; s > 0; s >>= 1) {
        if (tid < s) red[tid] += red[tid + s];
        __syncthreads();
    }
    if (tid == 0) {
        ms[0] = m;
        ms[1] = logf(red[0]);
    }
}

// ---------------- K4c: in-place log_softmax fixup ----------------
__global__ void logsoftmax_kernel(float* __restrict__ lp,
                                  const float* __restrict__ ms) {
    const int v = blockIdx.x * 256 + threadIdx.x;
    if (v < V) lp[v] = lp[v] - ms[0] - ms[1];
}

extern "C" void kernel_launch(void* const* d_in, const int* in_sizes, int n_in,
                              void* d_out, int out_size, void* d_ws, size_t ws_size,
                              hipStream_t stream) {
    const int*   ids    = (const int*)d_in[0];
    const float* hidden = (const float*)d_in[1];
    const float* enc    = (const float*)d_in[2];
    const float* emb    = (const float*)d_in[3];
    const float* W_ih   = (const float*)d_in[4];
    const float* W_hh   = (const float*)d_in[5];
    const float* b_ih   = (const float*)d_in[6];
    const float* b_hh   = (const float*)d_in[7];
    const float* W_comb = (const float*)d_in[8];
    const float* b_comb = (const float*)d_in[9];
    const float* W_out  = (const float*)d_in[10];
    const float* b_out  = (const float*)d_in[11];

    float* out = (float*)d_out;
    float* ws  = (float*)d_ws;

    float* lp       = out + OUT_LP;
    float* hnew     = out + OUT_H;
    float* out_attn = out + OUT_ATTN;

    float* alog = ws + WS_ALOG;
    float* ctx  = ws + WS_CTX;
    float* comb = ws + WS_COMB;
    float* pmax = ws + WS_PMAX;
    float* psum = ws + WS_PSUM;
    float* ms   = ws + WS_MS;

    gru_kernel<<<256, 256, 0, stream>>>(ids, hidden, emb, W_ih, W_hh, b_ih, b_hh, hnew);
    attnlogits_kernel<<<512, 256, 0, stream>>>(enc, hnew, alog, ctx);
    attn_ctx_kernel<<<64, 256, 0, stream>>>(enc, alog, ctx, out_attn);
    comb_kernel<<<256, 256, 0, stream>>>(W_comb, b_comb, ctx, hnew, comb);
    outproj_kernel<<<K4_NB, 256, 0, stream>>>(W_out, b_out, comb, lp, pmax, psum);
    lse_merge_kernel<<<1, 256, 0, stream>>>(pmax, psum, ms);
    logsoftmax_kernel<<<(V + 255) / 256, 256, 0, stream>>>(lp, ms);
}

// Round 2
// 434.286 us; speedup vs baseline: 1.0064x; 1.0064x over previous
//
#include <hip/hip_runtime.h>
#include <hip/hip_bf16.h>
#include <math.h>

#define H 1024
#define V 50257
#define S 2048

// d_out layout (floats): [0, V) log_probs | [V, V+H) h_new | [V+H, V+H+S) attn
#define OUT_LP   0
#define OUT_H    50257
#define OUT_ATTN 51281

// workspace layout (floats)
#define WS_ALOG 0        // 2048 attention logits
#define WS_CTX  2048     // 1024 context accumulator (zeroed by K2a)
#define WS_COMB 3072     // 1024 combined vector
#define WS_PMAX 4096     // 1571 per-block max
#define WS_PSUM 5696     // 1571 per-block sumexp

#define K4_NB 1571       // ceil(50257 / 32)

// ---------------- K1: embedding + relu + GRU cell -> h_new ----------------
__global__ __launch_bounds__(256) void gru_kernel(
        const int* __restrict__ ids,
        const float* __restrict__ hidden,
        const float* __restrict__ emb,
        const float* __restrict__ W_ih,
        const float* __restrict__ W_hh,
        const float* __restrict__ b_ih,
        const float* __restrict__ b_hh,
        float* __restrict__ hnew_out) {
    __shared__ float x_lds[H];
    __shared__ float h_lds[H];
    const int tid = threadIdx.x;
    const int row = ids[0];
    const float* erow = emb + (size_t)row * H;
    for (int i = tid; i < H; i += 256) {
        x_lds[i] = fmaxf(erow[i], 0.0f);
        h_lds[i] = hidden[i];
    }
    __syncthreads();

    const int lane = tid & 63;
    const int w    = tid >> 6;
    const int j    = blockIdx.x * 4 + w;   // grid = 256 blocks -> j in [0,1024)

    const float4* x4  = (const float4*)x_lds;
    const float4* h4  = (const float4*)h_lds;
    const float4* Wi4 = (const float4*)W_ih;
    const float4* Wh4 = (const float4*)W_hh;

    float air = 0.f, aiz = 0.f, ain = 0.f, ahr = 0.f, ahz = 0.f, ahn = 0.f;
#pragma unroll
    for (int i = 0; i < 4; ++i) {
        const int idx = i * 64 + lane;
        const float4 xv = x4[idx];
        const float4 hv = h4[idx];
        float4 a = Wi4[(size_t)j * 256 + idx];
        air += a.x * xv.x + a.y * xv.y + a.z * xv.z + a.w * xv.w;
        float4 b = Wi4[(size_t)(H + j) * 256 + idx];
        aiz += b.x * xv.x + b.y * xv.y + b.z * xv.z + b.w * xv.w;
        float4 c = Wi4[(size_t)(2 * H + j) * 256 + idx];
        ain += c.x * xv.x + c.y * xv.y + c.z * xv.z + c.w * xv.w;
        float4 d = Wh4[(size_t)j * 256 + idx];
        ahr += d.x * hv.x + d.y * hv.y + d.z * hv.z + d.w * hv.w;
        float4 e = Wh4[(size_t)(H + j) * 256 + idx];
        ahz += e.x * hv.x + e.y * hv.y + e.z * hv.z + e.w * hv.w;
        float4 f = Wh4[(size_t)(2 * H + j) * 256 + idx];
        ahn += f.x * hv.x + f.y * hv.y + f.z * hv.z + f.w * hv.w;
    }
#pragma unroll
    for (int off = 32; off > 0; off >>= 1) {
        air += __shfl_down(air, off);
        aiz += __shfl_down(aiz, off);
        ain += __shfl_down(ain, off);
        ahr += __shfl_down(ahr, off);
        ahz += __shfl_down(ahz, off);
        ahn += __shfl_down(ahn, off);
    }
    if (lane == 0) {
        const float gir = air + b_ih[j];
        const float giz = aiz + b_ih[H + j];
        const float gin = ain + b_ih[2 * H + j];
        const float ghr = ahr + b_hh[j];
        const float ghz = ahz + b_hh[H + j];
        const float ghn = ahn + b_hh[2 * H + j];
        const float r = 1.0f / (1.0f + expf(-(gir + ghr)));
        const float z = 1.0f / (1.0f + expf(-(giz + ghz)));
        const float n = tanhf(gin + r * ghn);
        hnew_out[j] = (1.0f - z) * n + z * h_lds[j];
    }
}

// ---------------- K2a: attention logits + zero ctx ----------------
__global__ __launch_bounds__(256) void attnlogits_kernel(
        const float* __restrict__ enc,
        const float* __restrict__ hnew,
        float* __restrict__ alog,
        float* __restrict__ ctx) {
    __shared__ float h_lds[H];
    const int tid = threadIdx.x;
    for (int i = tid; i < H; i += 256) h_lds[i] = hnew[i];
    if (blockIdx.x == 0) {
        for (int i = tid; i < H; i += 256) ctx[i] = 0.0f;
    }
    __syncthreads();

    const int lane = tid & 63;
    const int w    = tid >> 6;
    const int s    = blockIdx.x * 4 + w;   // grid = 512 blocks -> s in [0,2048)

    const float4* h4 = (const float4*)h_lds;
    const float4* e4 = (const float4*)(enc + (size_t)s * H);
    float acc = 0.f;
#pragma unroll
    for (int i = 0; i < 4; ++i) {
        const int idx = i * 64 + lane;
        const float4 ev = e4[idx];
        const float4 hv = h4[idx];
        acc += ev.x * hv.x + ev.y * hv.y + ev.z * hv.z + ev.w * hv.w;
    }
#pragma unroll
    for (int off = 32; off > 0; off >>= 1) acc += __shfl_down(acc, off);
    if (lane == 0) alog[s] = acc;
}

// ---------------- K2c: softmax + ctx accumulation + attn output ----------------
__global__ __launch_bounds__(256) void attn_ctx_kernel(
        const float* __restrict__ enc,
        const float* __restrict__ alog,
        float* __restrict__ ctx,
        float* __restrict__ out_attn) {
    __shared__ float l_lds[S];
    __shared__ float red[256];
    const int tid = threadIdx.x;
    for (int i = tid; i < S; i += 256) l_lds[i] = alog[i];
    __syncthreads();

    float m = -INFINITY;
    for (int i = tid; i < S; i += 256) m = fmaxf(m, l_lds[i]);
    red[tid] = m;
    __syncthreads();
    for (int s = 128; s > 0; s >>= 1) {
        if (tid < s) red[tid] = fmaxf(red[tid], red[tid + s]);
        __syncthreads();
    }
    m = red[0];
    __syncthreads();

    float ssum = 0.f;
    for (int i = tid; i < S; i += 256) ssum += expf(l_lds[i] - m);
    red[tid] = ssum;
    __syncthreads();
    for (int s = 128; s > 0; s >>= 1) {
        if (tid < s) red[tid] += red[tid + s];
        __syncthreads();
    }
    const float inv = 1.0f / red[0];

    const int s0 = blockIdx.x * 32;   // grid = 64 blocks
    float4 cacc = make_float4(0.f, 0.f, 0.f, 0.f);
    const float4* e4 = (const float4*)enc;
    for (int r = 0; r < 32; ++r) {
        const int srow = s0 + r;
        const float wgt = expf(l_lds[srow] - m) * inv;
        const float4 ev = e4[(size_t)srow * 256 + tid];
        cacc.x += wgt * ev.x;
        cacc.y += wgt * ev.y;
        cacc.z += wgt * ev.z;
        cacc.w += wgt * ev.w;
    }
    atomicAdd(&ctx[tid * 4 + 0], cacc.x);
    atomicAdd(&ctx[tid * 4 + 1], cacc.y);
    atomicAdd(&ctx[tid * 4 + 2], cacc.z);
    atomicAdd(&ctx[tid * 4 + 3], cacc.w);

    if (tid < 32) {
        const int srow = s0 + tid;
        out_attn[srow] = expf(l_lds[srow] - m) * inv;
    }
}

// ---------------- K3: comb = tanh(W_comb @ [ctx; h_new] + b_comb) ----------------
__global__ __launch_bounds__(256) void comb_kernel(
        const float* __restrict__ W_comb,
        const float* __restrict__ b_comb,
        const float* __restrict__ ctx,
        const float* __restrict__ hnew,
        float* __restrict__ comb) {
    __shared__ float cat_lds[2 * H];
    const int tid = threadIdx.x;
    for (int i = tid; i < H; i += 256) {
        cat_lds[i]     = ctx[i];
        cat_lds[H + i] = hnew[i];
    }
    __syncthreads();

    const int lane = tid & 63;
    const int w    = tid >> 6;
    const int j    = blockIdx.x * 4 + w;   // grid = 256 blocks

    const float4* c4 = (const float4*)cat_lds;
    const float4* W4 = (const float4*)(W_comb + (size_t)j * 2 * H);
    float acc = 0.f;
#pragma unroll
    for (int i = 0; i < 8; ++i) {
        const int idx = i * 64 + lane;
        const float4 wv = W4[idx];
        const float4 cv = c4[idx];
        acc += wv.x * cv.x + wv.y * cv.y + wv.z * cv.z + wv.w * cv.w;
    }
#pragma unroll
    for (int off = 32; off > 0; off >>= 1) acc += __shfl_down(acc, off);
    if (lane == 0) comb[j] = tanhf(acc + b_comb[j]);
}

// ---------------- K4a: logits = W_out @ comb + b_out, per-block (max,sumexp) ----------------
__global__ __launch_bounds__(256) void outproj_kernel(
        const float* __restrict__ Wout,
        const float* __restrict__ bout,
        const float* __restrict__ comb,
        float* __restrict__ logits_out,
        float* __restrict__ pmax,
        float* __restrict__ psum) {
    __shared__ float c_lds[H];
    __shared__ float l_blk[32];
    const int tid = threadIdx.x;
    for (int i = tid; i < H; i += 256) c_lds[i] = comb[i];
    __syncthreads();

    const int lane = tid & 63;
    const int w    = tid >> 6;
    const float4* c4 = (const float4*)c_lds;
    const int rbase = (blockIdx.x * 4 + w) * 8;   // 8 rows per wave, 32 per block

    for (int r = 0; r < 8; ++r) {
        const int row = rbase + r;
        float acc = 0.f;
        if (row < V) {
            const float4* W4 = (const float4*)(Wout + (size_t)row * H);
#pragma unroll
            for (int i = 0; i < 4; ++i) {
                const int idx = i * 64 + lane;
                const float4 wv = W4[idx];
                const float4 cv = c4[idx];
                acc += wv.x * cv.x + wv.y * cv.y + wv.z * cv.z + wv.w * cv.w;
            }
        }
#pragma unroll
        for (int off = 32; off > 0; off >>= 1) acc += __shfl_down(acc, off);
        if (lane == 0) {
            float l = -INFINITY;
            if (row < V) {
                l = acc + bout[row];
                logits_out[row] = l;
            }
            l_blk[w * 8 + r] = l;
        }
    }
    __syncthreads();
    if (tid == 0) {
        float m = -INFINITY;
#pragma unroll
        for (int i = 0; i < 32; ++i) m = fmaxf(m, l_blk[i]);
        float ssum = 0.f;
#pragma unroll
        for (int i = 0; i < 32; ++i) ssum += expf(l_blk[i] - m);
        pmax[blockIdx.x] = m;
        psum[blockIdx.x] = ssum;
    }
}

// ---------------- K4b (fused): per-block redundant LSE merge + in-place fixup ----------------
__global__ __launch_bounds__(256) void logsoftmax_fused_kernel(
        float* __restrict__ lp,
        const float* __restrict__ pmax,
        const float* __restrict__ psum) {
    __shared__ float red[256];
    const int tid = threadIdx.x;

    // redundant merge of 1571 (max,sumexp) pairs -- L2-resident, ~13 KB/block
    float m = -INFINITY;
    for (int i = tid; i < K4_NB; i += 256) m = fmaxf(m, pmax[i]);
    red[tid] = m;
    __syncthreads();
    for (int s = 128; s > 0; s >>= 1) {
        if (tid < s) red[tid] = fmaxf(red[tid], red[tid + s]);
        __syncthreads();
    }
    m = red[0];
    __syncthreads();
    float ssum = 0.f;
    for (int i = tid; i < K4_NB; i += 256) ssum += psum[i] * expf(pmax[i] - m);
    red[tid] = ssum;
    __syncthreads();
    for (int s = 128; s > 0; s >>= 1) {
        if (tid < s) red[tid] += red[tid + s];
        __syncthreads();
    }
    const float shift = m + logf(red[0]);

    const int v = blockIdx.x * 256 + tid;
    if (v < V) lp[v] = lp[v] - shift;
}

extern "C" void kernel_launch(void* const* d_in, const int* in_sizes, int n_in,
                              void* d_out, int out_size, void* d_ws, size_t ws_size,
                              hipStream_t stream) {
    const int*   ids    = (const int*)d_in[0];
    const float* hidden = (const float*)d_in[1];
    const float* enc    = (const float*)d_in[2];
    const float* emb    = (const float*)d_in[3];
    const float* W_ih   = (const float*)d_in[4];
    const float* W_hh   = (const float*)d_in[5];
    const float* b_ih   = (const float*)d_in[6];
    const float* b_hh   = (const float*)d_in[7];
    const float* W_comb = (const float*)d_in[8];
    const float* b_comb = (const float*)d_in[9];
    const float* W_out  = (const float*)d_in[10];
    const float* b_out  = (const float*)d_in[11];

    float* out = (float*)d_out;
    float* ws  = (float*)d_ws;

    float* lp       = out + OUT_LP;
    float* hnew     = out + OUT_H;
    float* out_attn = out + OUT_ATTN;

    float* alog = ws + WS_ALOG;
    float* ctx  = ws + WS_CTX;
    float* comb = ws + WS_COMB;
    float* pmax = ws + WS_PMAX;
    float* psum = ws + WS_PSUM;

    gru_kernel<<<256, 256, 0, stream>>>(ids, hidden, emb, W_ih, W_hh, b_ih, b_hh, hnew);
    attnlogits_kernel<<<512, 256, 0, stream>>>(enc, hnew, alog, ctx);
    attn_ctx_kernel<<<64, 256, 0, stream>>>(enc, alog, ctx, out_attn);
    comb_kernel<<<256, 256, 0, stream>>>(W_comb, b_comb, ctx, hnew, comb);
    outproj_kernel<<<K4_NB, 256, 0, stream>>>(W_out, b_out, comb, lp, pmax, psum);
    logsoftmax_fused_kernel<<<(V + 255) / 256, 256, 0, stream>>>(lp, pmax, psum);
}